// Round 6
// baseline (323.993 us; speedup 1.0000x reference)
//
#include <hip/hip_runtime.h>

#define TEMP 0.05f
#define EPS 1e-8f
#define NROWS 16384
#define DDIM 1024
#define NBLOCKS (NROWS / 4)   // 4 waves/block, 1 row/wave (round-3 geometry)

typedef float vf4 __attribute__((ext_vector_type(4)));

__global__ __launch_bounds__(256) void byol_fused_kernel(
        const float* __restrict__ a, const float* __restrict__ b,
        float* __restrict__ partials, unsigned int* __restrict__ ticket,
        float* __restrict__ out) {
    const int wave = threadIdx.x >> 6;
    const int lane = threadIdx.x & 63;
    const int row  = blockIdx.x * 4 + wave;

    const vf4* a4 = (const vf4*)(a + (size_t)row * DDIM);
    const vf4* b4 = (const vf4*)(b + (size_t)row * DDIM);

    // 8-deep nontemporal load batch (128 B/lane in flight), then math.
    vf4 av[4], bv[4];
#pragma unroll
    for (int j = 0; j < 4; ++j)
        av[j] = __builtin_nontemporal_load(&a4[lane + 64 * j]);
#pragma unroll
    for (int j = 0; j < 4; ++j)
        bv[j] = __builtin_nontemporal_load(&b4[lane + 64 * j]);

    float dot = 0.f, aa = 0.f, bb = 0.f;
#pragma unroll
    for (int j = 0; j < 4; ++j) {
        dot += av[j].x * bv[j].x + av[j].y * bv[j].y
             + av[j].z * bv[j].z + av[j].w * bv[j].w;
        aa  += av[j].x * av[j].x + av[j].y * av[j].y
             + av[j].z * av[j].z + av[j].w * av[j].w;
        bb  += bv[j].x * bv[j].x + bv[j].y * bv[j].y
             + bv[j].z * bv[j].z + bv[j].w * bv[j].w;
    }

#pragma unroll
    for (int off = 32; off > 0; off >>= 1) {
        dot += __shfl_down(dot, off, 64);
        aa  += __shfl_down(aa,  off, 64);
        bb  += __shfl_down(bb,  off, 64);
    }

    __shared__ float s[4];
    __shared__ bool amLast;
    if (lane == 0) {
        float n1 = fmaxf(sqrtf(aa), EPS);
        float n2 = fmaxf(sqrtf(bb), EPS);
        float c  = dot / (n1 * n2);
        s[wave]  = 2.0f - 2.0f * c;
    }
    __syncthreads();

    // Last-block reduction (canonical threadfence-reduction pattern).
    // Device-scope fence is required for cross-XCD visibility (G16).
    if (threadIdx.x == 0) {
        partials[blockIdx.x] = s[0] + s[1] + s[2] + s[3];
        __threadfence();                              // release: partial visible device-wide
        unsigned int t = atomicAdd(ticket, 1u);       // device-scope by default
        amLast = (t == NBLOCKS - 1);
    }
    __syncthreads();
    if (!amLast) return;                              // amLast is block-uniform

    __threadfence();                                  // acquire: see all partials

    // Bit-identical summation order to the previous byol_final_kernel.
    float sum = 0.f;
#pragma unroll
    for (int j = 0; j < NBLOCKS / 256; ++j)
        sum += partials[threadIdx.x + 256 * j];

#pragma unroll
    for (int off = 32; off > 0; off >>= 1)
        sum += __shfl_down(sum, off, 64);

    __syncthreads();                                  // reuse s[] safely
    if (lane == 0) s[wave] = sum;
    __syncthreads();
    if (threadIdx.x == 0) {
        out[0] = (s[0] + s[1] + s[2] + s[3]) * (1.0f / ((float)NROWS * TEMP));
    }
}

extern "C" void kernel_launch(void* const* d_in, const int* in_sizes, int n_in,
                              void* d_out, int out_size, void* d_ws, size_t ws_size,
                              hipStream_t stream) {
    const float* a = (const float*)d_in[0];
    const float* b = (const float*)d_in[1];
    float* out = (float*)d_out;
    float* partials = (float*)d_ws;                          // NBLOCKS floats = 16 KB
    unsigned int* ticket = (unsigned int*)((char*)d_ws + NBLOCKS * sizeof(float));
    // ws_size >= 32 KB (round 4 used 8192 floats successfully) -> ticket in-bounds.

    // Workspace is poisoned every iteration: zero the ticket (graph-capturable).
    hipMemsetAsync(ticket, 0, sizeof(unsigned int), stream);

    byol_fused_kernel<<<NBLOCKS, 256, 0, stream>>>(a, b, partials, ticket, out);
}

// Round 7
// 137.818 us; speedup vs baseline: 2.3509x; 2.3509x over previous
//
#include <hip/hip_runtime.h>

#define TEMP 0.05f
#define EPS 1e-8f
#define NROWS 16384
#define DDIM 1024
#define NBLOCKS (NROWS / 4)   // 4 waves/block, 1 row/wave (round-3 geometry, best: 134.9 us)

typedef float vf4 __attribute__((ext_vector_type(4)));

__global__ __launch_bounds__(256) void byol_rows_kernel(
        const float* __restrict__ a, const float* __restrict__ b,
        float* __restrict__ partials) {
    const int wave = threadIdx.x >> 6;
    const int lane = threadIdx.x & 63;
    const int row  = blockIdx.x * 4 + wave;

    const vf4* a4 = (const vf4*)(a + (size_t)row * DDIM);
    const vf4* b4 = (const vf4*)(b + (size_t)row * DDIM);

    // 8-deep nontemporal load batch (128 B/lane in flight), then math.
    vf4 av[4], bv[4];
#pragma unroll
    for (int j = 0; j < 4; ++j)
        av[j] = __builtin_nontemporal_load(&a4[lane + 64 * j]);
#pragma unroll
    for (int j = 0; j < 4; ++j)
        bv[j] = __builtin_nontemporal_load(&b4[lane + 64 * j]);

    float dot = 0.f, aa = 0.f, bb = 0.f;
#pragma unroll
    for (int j = 0; j < 4; ++j) {
        dot += av[j].x * bv[j].x + av[j].y * bv[j].y
             + av[j].z * bv[j].z + av[j].w * bv[j].w;
        aa  += av[j].x * av[j].x + av[j].y * av[j].y
             + av[j].z * av[j].z + av[j].w * av[j].w;
        bb  += bv[j].x * bv[j].x + bv[j].y * bv[j].y
             + bv[j].z * bv[j].z + bv[j].w * bv[j].w;
    }

#pragma unroll
    for (int off = 32; off > 0; off >>= 1) {
        dot += __shfl_down(dot, off, 64);
        aa  += __shfl_down(aa,  off, 64);
        bb  += __shfl_down(bb,  off, 64);
    }

    __shared__ float s[4];
    if (lane == 0) {
        float n1 = fmaxf(sqrtf(aa), EPS);
        float n2 = fmaxf(sqrtf(bb), EPS);
        float c  = dot / (n1 * n2);
        s[wave]  = 2.0f - 2.0f * c;
    }
    __syncthreads();
    if (threadIdx.x == 0) {
        partials[blockIdx.x] = s[0] + s[1] + s[2] + s[3];
    }
}

// 1024 threads: 4 nt-loads/thread (vs 16 sequential cold scalar loads on 256
// threads) -> shorter latency chain on the cross-XCD partials read.
__global__ __launch_bounds__(1024) void byol_final_kernel(
        const float* __restrict__ partials, float* __restrict__ out) {
    const int wave = threadIdx.x >> 6;
    const int lane = threadIdx.x & 63;

    float sum = 0.f;
#pragma unroll
    for (int j = 0; j < NBLOCKS / 1024; ++j)
        sum += __builtin_nontemporal_load(&partials[threadIdx.x + 1024 * j]);

#pragma unroll
    for (int off = 32; off > 0; off >>= 1)
        sum += __shfl_down(sum, off, 64);

    __shared__ float s[16];
    if (lane == 0) s[wave] = sum;
    __syncthreads();
    if (wave == 0) {
        float v = (lane < 16) ? s[lane] : 0.f;
#pragma unroll
        for (int off = 8; off > 0; off >>= 1)
            v += __shfl_down(v, off, 64);
        if (lane == 0)
            out[0] = v * (1.0f / ((float)NROWS * TEMP));
    }
}

extern "C" void kernel_launch(void* const* d_in, const int* in_sizes, int n_in,
                              void* d_out, int out_size, void* d_ws, size_t ws_size,
                              hipStream_t stream) {
    const float* a = (const float*)d_in[0];
    const float* b = (const float*)d_in[1];
    float* out = (float*)d_out;
    float* partials = (float*)d_ws;   // NBLOCKS floats = 16 KB

    byol_rows_kernel<<<NBLOCKS, 256, 0, stream>>>(a, b, partials);
    byol_final_kernel<<<1, 1024, 0, stream>>>(partials, out);
}

// Round 8
// 135.757 us; speedup vs baseline: 2.3866x; 1.0152x over previous
//
#include <hip/hip_runtime.h>

#define TEMP 0.05f
#define EPS 1e-8f
#define NROWS 16384
#define DDIM 1024
#define NBLOCKS (NROWS / 4)   // 4 waves/block, 1 row/wave (round-3 geometry, best: 134.9 us)

typedef float vf4 __attribute__((ext_vector_type(4)));

__global__ __launch_bounds__(256) void byol_rows_kernel(
        const float* __restrict__ a, const float* __restrict__ b,
        float* __restrict__ partials) {
    const int wave = threadIdx.x >> 6;
    const int lane = threadIdx.x & 63;
    const int row  = blockIdx.x * 4 + wave;

    const vf4* a4 = (const vf4*)(a + (size_t)row * DDIM);
    const vf4* b4 = (const vf4*)(b + (size_t)row * DDIM);

    // 8-deep nontemporal load batch (128 B/lane in flight), then math.
    // nt bypasses L1 allocation on this zero-reuse streaming read: +8 us vs
    // plain loads (round 0 -> round 3). Deeper batches / fewer blocks do NOT
    // help further (rounds 1/4): read path sits at its MLP x latency
    // equilibrium (~3.7 TB/s effective on the ~50% L3-hit mix).
    vf4 av[4], bv[4];
#pragma unroll
    for (int j = 0; j < 4; ++j)
        av[j] = __builtin_nontemporal_load(&a4[lane + 64 * j]);
#pragma unroll
    for (int j = 0; j < 4; ++j)
        bv[j] = __builtin_nontemporal_load(&b4[lane + 64 * j]);

    float dot = 0.f, aa = 0.f, bb = 0.f;
#pragma unroll
    for (int j = 0; j < 4; ++j) {
        dot += av[j].x * bv[j].x + av[j].y * bv[j].y
             + av[j].z * bv[j].z + av[j].w * bv[j].w;
        aa  += av[j].x * av[j].x + av[j].y * av[j].y
             + av[j].z * av[j].z + av[j].w * av[j].w;
        bb  += bv[j].x * bv[j].x + bv[j].y * bv[j].y
             + bv[j].z * bv[j].z + bv[j].w * bv[j].w;
    }

#pragma unroll
    for (int off = 32; off > 0; off >>= 1) {
        dot += __shfl_down(dot, off, 64);
        aa  += __shfl_down(aa,  off, 64);
        bb  += __shfl_down(bb,  off, 64);
    }

    __shared__ float s[4];
    if (lane == 0) {
        float n1 = fmaxf(sqrtf(aa), EPS);
        float n2 = fmaxf(sqrtf(bb), EPS);
        float c  = dot / (n1 * n2);
        s[wave]  = 2.0f - 2.0f * c;
    }
    __syncthreads();
    if (threadIdx.x == 0) {
        partials[blockIdx.x] = s[0] + s[1] + s[2] + s[3];
    }
}

// Two-kernel structure is deliberate: fusing via a device-scope ticket atomic
// cost 44 ns/atomic across XCDs (round 6: 215 us). Plain 256-thread final
// kernel; partials are L2-resident, cached reads are fine (nt variant was
// neutral-to-worse, round 7).
__global__ __launch_bounds__(256) void byol_final_kernel(
        const float* __restrict__ partials, float* __restrict__ out) {
    float sum = 0.f;
#pragma unroll
    for (int j = 0; j < NBLOCKS / 256; ++j)
        sum += partials[threadIdx.x + 256 * j];

#pragma unroll
    for (int off = 32; off > 0; off >>= 1)
        sum += __shfl_down(sum, off, 64);

    __shared__ float s[4];
    const int wave = threadIdx.x >> 6;
    const int lane = threadIdx.x & 63;
    if (lane == 0) s[wave] = sum;
    __syncthreads();
    if (threadIdx.x == 0) {
        out[0] = (s[0] + s[1] + s[2] + s[3]) * (1.0f / ((float)NROWS * TEMP));
    }
}

extern "C" void kernel_launch(void* const* d_in, const int* in_sizes, int n_in,
                              void* d_out, int out_size, void* d_ws, size_t ws_size,
                              hipStream_t stream) {
    const float* a = (const float*)d_in[0];
    const float* b = (const float*)d_in[1];
    float* out = (float*)d_out;
    float* partials = (float*)d_ws;   // NBLOCKS floats = 16 KB

    byol_rows_kernel<<<NBLOCKS, 256, 0, stream>>>(a, b, partials);
    byol_final_kernel<<<1, 256, 0, stream>>>(partials, out);
}